// Round 8
// baseline (53582.404 us; speedup 1.0000x reference)
//
#include <hip/hip_runtime.h>
#include <hip/hip_bf16.h>
#include <math.h>

#define B_SZ 128
#define T_SZ 2048
#define NI 512
#define NH 512

// ---------------------------------------------------------------------------
// Kernel 0: pack W_hh into bf16-pair, k-blocked layout in d_ws.
//   wt3[kk4*512 + j] (uint4), dword q (0..3) = pack( bf16(W[8kk4+2q][j]),
//                                                    bf16(W[8kk4+2q+1][j]) )
// ---------------------------------------------------------------------------
__device__ __forceinline__ unsigned bf16_rne(float f) {
    unsigned u = __float_as_uint(f);
    return (u + 0x7fffu + ((u >> 16) & 1u)) >> 16;   // round-nearest-even
}

__global__ __launch_bounds__(256) void pack_whh(
    const float* __restrict__ W, uint4* __restrict__ wt3)
{
    const int idx = blockIdx.x * 256 + threadIdx.x;  // = kk4*512 + j
    const int j   = idx & 511;
    const int kk4 = idx >> 9;
    const int k0  = kk4 * 8;
    unsigned d[4];
    #pragma unroll
    for (int q = 0; q < 4; ++q) {
        const unsigned lo = bf16_rne(W[(size_t)(k0 + 2 * q)     * NH + j]);
        const unsigned hi = bf16_rne(W[(size_t)(k0 + 2 * q + 1) * NH + j]);
        d[q] = lo | (hi << 16);
    }
    wt3[idx] = make_uint4(d[0], d[1], d[2], d[3]);
}

// ---------------------------------------------------------------------------
// Kernel 1: x_proj = inputs @ W_xh + b_h, in-place into d_out's outs region.
// ~84% of fp32 VALU roofline -- unchanged since round 1.
// ---------------------------------------------------------------------------
#define BM 64
#define BN 64
#define BK 16

__global__ __launch_bounds__(256) void proj_gemm(
    const float* __restrict__ A,      // inputs [M=B*T, K=NI]
    const float* __restrict__ W,      // W_xh [K, N]
    const float* __restrict__ bias,   // b_h [N]
    float* __restrict__ C)            // d_out outs region [M, N]
{
    __shared__ float As[BK][BM];
    __shared__ float Bs[BK][BN];
    const int m0 = blockIdx.y * BM;
    const int n0 = blockIdx.x * BN;
    const int tid = threadIdx.x;
    const int tx = tid & 15;
    const int ty = tid >> 4;

    const int ar = tid >> 2;
    const int ac = (tid & 3) * 4;
    const int bk = tid >> 4;
    const int bn = (tid & 15) * 4;

    float acc[4][4] = {};

    for (int k0 = 0; k0 < NI; k0 += BK) {
        float4 av = *reinterpret_cast<const float4*>(
            &A[(size_t)(m0 + ar) * NI + k0 + ac]);
        float4 bv = *reinterpret_cast<const float4*>(
            &W[(size_t)(k0 + bk) * NH + n0 + bn]);
        __syncthreads();
        As[ac + 0][ar] = av.x;
        As[ac + 1][ar] = av.y;
        As[ac + 2][ar] = av.z;
        As[ac + 3][ar] = av.w;
        *reinterpret_cast<float4*>(&Bs[bk][bn]) = bv;
        __syncthreads();
        #pragma unroll
        for (int kk = 0; kk < BK; ++kk) {
            float a[4], b[4];
            #pragma unroll
            for (int i = 0; i < 4; ++i) a[i] = As[kk][ty * 4 + i];
            #pragma unroll
            for (int jj = 0; jj < 4; ++jj) b[jj] = Bs[kk][tx * 4 + jj];
            #pragma unroll
            for (int i = 0; i < 4; ++i)
                #pragma unroll
                for (int jj = 0; jj < 4; ++jj)
                    acc[i][jj] = fmaf(a[i], b[jj], acc[i][jj]);
        }
    }

    #pragma unroll
    for (int i = 0; i < 4; ++i) {
        const size_t row = (size_t)(m0 + ty * 4 + i);
        #pragma unroll
        for (int jj = 0; jj < 4; ++jj) {
            const int col = n0 + tx * 4 + jj;
            C[row * NH + col] = acc[i][jj] + bias[col];
        }
    }
}

// ---------------------------------------------------------------------------
// Kernel 2: ZERO-SYNC scan, quarter-k layout.
// 1 chain per WG (1024 thr, 16 waves), 128 WGs. Thread (q = tid>>8, u =
// tid&255) owns columns {u, u+256} over k-quarter [128q, 128q+128) =
// 16 blocks of 8 k. Two levers vs round 6:
//   (a) 2 cols/lane: each h-broadcast float4-pair feeds TWO FMA8s ->
//       LDS broadcast instrs per step 1024 -> 512.
//   (b) blocks 16q+0..3 (16 total, 128 KB) LDS-resident, loaded once ->
//       L2 stream 512 KB -> 384 KB per step.
// No register-W (refuted r2/r4/r7: compiler spills 64-reg slabs -> scratch
// catastrophe). In-loop stream loads, round-6 codegen style (VGPR ~48).
// Per-step: ps[q][col] partials -> barrier -> 512 reduce threads: sum 4
// quarters + xp, tanh, store out + h[nxt] -> barrier. 2 barriers/step.
// ---------------------------------------------------------------------------
#define FMA8A(ACC, WV, HA, HB)                                          \
    do {                                                                \
        ACC = fmaf((HA).x, __uint_as_float((WV).x << 16),         ACC); \
        ACC = fmaf((HA).y, __uint_as_float((WV).x & 0xffff0000u), ACC); \
        ACC = fmaf((HA).z, __uint_as_float((WV).y << 16),         ACC); \
        ACC = fmaf((HA).w, __uint_as_float((WV).y & 0xffff0000u), ACC); \
        ACC = fmaf((HB).x, __uint_as_float((WV).z << 16),         ACC); \
        ACC = fmaf((HB).y, __uint_as_float((WV).z & 0xffff0000u), ACC); \
        ACC = fmaf((HB).z, __uint_as_float((WV).w << 16),         ACC); \
        ACC = fmaf((HB).w, __uint_as_float((WV).w & 0xffff0000u), ACC); \
    } while (0)

__global__ __launch_bounds__(1024, 4) void rnn_scan_q(
    const uint4* __restrict__ wt3,   // packed W_hh [64][512] uint4
    const float* __restrict__ H0,    // [128][512]
    float* __restrict__ out,         // [128][2048][512]: xp on entry -> h
    float* __restrict__ hT)          // [128][512]
{
    __shared__ uint4 wlds[16][512];  // 128 KB: blocks 16q+0..3, q=0..3
    __shared__ float h[2][NH];       // 4 KB double buffer
    __shared__ float ps[4][NH];      // 8 KB quarter partials

    const int tid = threadIdx.x;
    const int b   = blockIdx.x;
    const int q   = tid >> 8;        // k-quarter 0..3 (wave-uniform)
    const int u   = tid & 255;       // col-pair base: cols u, u+256

    // --- stage LDS-resident W blocks (once): 8192 uint4, 8 per thread ---
    #pragma unroll
    for (int pass = 0; pass < 8; ++pass) {
        const int idx = pass * 1024 + tid;   // 0..8191
        const int bq  = idx >> 11;           // quarter 0..3
        const int bi  = (idx >> 9) & 3;      // block-in-quarter 0..3
        const int col = idx & 511;
        wlds[bq * 4 + bi][col] = wt3[(size_t)(bq * 16 + bi) * 512 + col];
    }
    if (tid < NH) h[0][tid] = H0[(size_t)b * NH + tid];
    __syncthreads();   // wlds + h0 ready

    float* outrow = out + (size_t)b * T_SZ * NH + tid;   // reduce role, tid<512
    float xp_cur = (tid < NH) ? outrow[0] : 0.f;
    int cur = 0;
    float hv = 0.f;

    const uint4* wq0 = wt3 + (size_t)(q * 16) * 512 + u;   // col u, quarter base
    const uint4* wq1 = wq0 + 256;                           // col u+256

    for (int t = 0; t < T_SZ; ++t) {
        float xp_next = 0.f;
        if (tid < NH && t + 1 < T_SZ)
            xp_next = __builtin_nontemporal_load(outrow + (size_t)(t + 1) * NH);

        const float4* hq = reinterpret_cast<const float4*>(h[cur]) + q * 32;
        float a0 = 0.f, a1 = 0.f;
        #pragma unroll
        for (int blk = 0; blk < 16; ++blk) {
            uint4 w0, w1;
            if (blk < 4) {                       // LDS-resident blocks
                w0 = wlds[q * 4 + blk][u];
                w1 = wlds[q * 4 + blk][u + 256];
            } else {                             // streamed from L2
                w0 = wq0[(size_t)blk * 512];
                w1 = wq1[(size_t)blk * 512];
            }
            const float4 hA = hq[blk * 2];       // wave-uniform -> broadcast
            const float4 hB = hq[blk * 2 + 1];   // (shared by both columns)
            FMA8A(a0, w0, hA, hB);
            FMA8A(a1, w1, hA, hB);
        }
        ps[q][u]       = a0;
        ps[q][u + 256] = a1;
        __syncthreads();   // s1: partials visible

        if (tid < NH) {
            const float s = ps[0][tid] + ps[1][tid] + ps[2][tid] + ps[3][tid];
            hv = tanhf(s + xp_cur);
            __builtin_nontemporal_store(hv, outrow + (size_t)t * NH);
            h[cur ^ 1][tid] = hv;
            xp_cur = xp_next;
        }
        __syncthreads();   // s2: h[cur^1] complete, ps reads done
        cur ^= 1;
    }
    if (tid < NH) hT[(size_t)b * NH + tid] = hv;
}

// ---------------------------------------------------------------------------
extern "C" void kernel_launch(void* const* d_in, const int* in_sizes, int n_in,
                              void* d_out, int out_size, void* d_ws, size_t ws_size,
                              hipStream_t stream) {
    const float* inputs = (const float*)d_in[0];   // [B, T, NI]
    const float* H0     = (const float*)d_in[1];   // [B, NH]
    const float* W_xh   = (const float*)d_in[2];   // [NI, NH]
    const float* W_hh   = (const float*)d_in[3];   // [NH, NH]
    const float* b_h    = (const float*)d_in[4];   // [NH]

    float* out = (float*)d_out;                        // outs [B,T,NH]
    float* hT  = out + (size_t)B_SZ * T_SZ * NH;       // H_T [B,NH]

    uint4* wt3 = (uint4*)d_ws;                         // 512 KB packed W_hh

    // 0) pack W_hh -> bf16 pairs (deterministic, rewritten every launch)
    pack_whh<<<128, 256, 0, stream>>>(W_hh, wt3);

    // 1) input projection -> d_out outs region
    dim3 g1(NH / BN, (B_SZ * T_SZ) / BM);  // (8, 4096)
    proj_gemm<<<g1, 256, 0, stream>>>(inputs, W_xh, b_h, out);

    // 2) zero-sync recurrence: one 1024-thread WG per chain, quarter-k
    rnn_scan_q<<<128, 1024, 0, stream>>>(wt3, H0, out, hT);
}

// Round 9
// 9528.346 us; speedup vs baseline: 5.6235x; 5.6235x over previous
//
#include <hip/hip_runtime.h>
#include <hip/hip_bf16.h>
#include <hip/hip_fp16.h>
#include <math.h>

#define B_SZ 128
#define T_SZ 2048
#define NI 512
#define NH 512

// ---------------------------------------------------------------------------
// f16 pair dot: D = w.lo*h.lo + w.hi*h.hi + acc  (v_dot2_f32_f16)
// ---------------------------------------------------------------------------
typedef _Float16 h2_t __attribute__((ext_vector_type(2)));

__device__ __forceinline__ float dot2p(unsigned w, unsigned h, float acc) {
#if __has_builtin(__builtin_amdgcn_fdot2)
    return __builtin_amdgcn_fdot2(__builtin_bit_cast(h2_t, w),
                                  __builtin_bit_cast(h2_t, h), acc, false);
#else
    const h2_t wv = __builtin_bit_cast(h2_t, w);
    const h2_t hv = __builtin_bit_cast(h2_t, h);
    acc = fmaf((float)wv.x, (float)hv.x, acc);
    acc = fmaf((float)wv.y, (float)hv.y, acc);
    return acc;
#endif
}

#define DOT_BLK(WV, HV)                      \
    do {                                     \
        acc = dot2p((WV).x, (HV).x, acc);    \
        acc = dot2p((WV).y, (HV).y, acc);    \
        acc = dot2p((WV).z, (HV).z, acc);    \
        acc = dot2p((WV).w, (HV).w, acc);    \
    } while (0)

// ---------------------------------------------------------------------------
// Kernel 0: pack W_hh into f16-pair, k-blocked layout in d_ws.
//   wt3[kk4*512 + j] (uint4), dword q = pack( f16(W[8kk4+2q][j]),
//                                             f16(W[8kk4+2q+1][j]) )
// ---------------------------------------------------------------------------
__global__ __launch_bounds__(256) void pack_whh(
    const float* __restrict__ W, uint4* __restrict__ wt3)
{
    const int idx = blockIdx.x * 256 + threadIdx.x;  // = kk4*512 + j
    const int j   = idx & 511;
    const int kk4 = idx >> 9;
    const int k0  = kk4 * 8;
    unsigned d[4];
    #pragma unroll
    for (int q = 0; q < 4; ++q) {
        const unsigned lo =
            __half_as_ushort(__float2half_rn(W[(size_t)(k0 + 2 * q)     * NH + j]));
        const unsigned hi =
            __half_as_ushort(__float2half_rn(W[(size_t)(k0 + 2 * q + 1) * NH + j]));
        d[q] = lo | (hi << 16);
    }
    wt3[idx] = make_uint4(d[0], d[1], d[2], d[3]);
}

// ---------------------------------------------------------------------------
// Kernel 1: x_proj = inputs @ W_xh + b_h, in-place into d_out's outs region.
// ~84% of fp32 VALU roofline -- unchanged since round 1.
// ---------------------------------------------------------------------------
#define BM 64
#define BN 64
#define BK 16

__global__ __launch_bounds__(256) void proj_gemm(
    const float* __restrict__ A,      // inputs [M=B*T, K=NI]
    const float* __restrict__ W,      // W_xh [K, N]
    const float* __restrict__ bias,   // b_h [N]
    float* __restrict__ C)            // d_out outs region [M, N]
{
    __shared__ float As[BK][BM];
    __shared__ float Bs[BK][BN];
    const int m0 = blockIdx.y * BM;
    const int n0 = blockIdx.x * BN;
    const int tid = threadIdx.x;
    const int tx = tid & 15;
    const int ty = tid >> 4;

    const int ar = tid >> 2;
    const int ac = (tid & 3) * 4;
    const int bk = tid >> 4;
    const int bn = (tid & 15) * 4;

    float acc[4][4] = {};

    for (int k0 = 0; k0 < NI; k0 += BK) {
        float4 av = *reinterpret_cast<const float4*>(
            &A[(size_t)(m0 + ar) * NI + k0 + ac]);
        float4 bv = *reinterpret_cast<const float4*>(
            &W[(size_t)(k0 + bk) * NH + n0 + bn]);
        __syncthreads();
        As[ac + 0][ar] = av.x;
        As[ac + 1][ar] = av.y;
        As[ac + 2][ar] = av.z;
        As[ac + 3][ar] = av.w;
        *reinterpret_cast<float4*>(&Bs[bk][bn]) = bv;
        __syncthreads();
        #pragma unroll
        for (int kk = 0; kk < BK; ++kk) {
            float a[4], b[4];
            #pragma unroll
            for (int i = 0; i < 4; ++i) a[i] = As[kk][ty * 4 + i];
            #pragma unroll
            for (int jj = 0; jj < 4; ++jj) b[jj] = Bs[kk][tx * 4 + jj];
            #pragma unroll
            for (int i = 0; i < 4; ++i)
                #pragma unroll
                for (int jj = 0; jj < 4; ++jj)
                    acc[i][jj] = fmaf(a[i], b[jj], acc[i][jj]);
        }
    }

    #pragma unroll
    for (int i = 0; i < 4; ++i) {
        const size_t row = (size_t)(m0 + ty * 4 + i);
        #pragma unroll
        for (int jj = 0; jj < 4; ++jj) {
            const int col = n0 + tx * 4 + jj;
            C[row * NH + col] = acc[i][jj] + bias[col];
        }
    }
}

// ---------------------------------------------------------------------------
// Kernel 2: ZERO-SYNC scan, f16 dot2, round-6 codegen skeleton.
// 1 chain/WG (1024 thr, 16 waves), 128 WGs. Thread (j=tid&511, half=tid>>9)
// owns column j over k-half [256*half, 256*half+256) = 32 blocks of 8 k:
//   blocks 0..7   -> LDS-resident (wlds, 128 KB, staged once)
//   blocks 8..31  -> streamed from L2 (384 KB/step, ~2.7us floor)
// Body: 8 groups of [1 resident blk + 3 stream blks], single acc chain,
// each load consumed immediately (r6's proven codegen profile; r7/r8's
// spill trigger -- big batched VMEM clauses / mixed-select unrolled loop --
// avoided). wt3/out NOT __restrict__ (anti-LICM insurance).
// h kept as packed f16 pairs in LDS (uint per 2 k): halves h traffic and
// feeds v_dot2_f32_f16 directly -- per-thread VALU 512 ops -> ~128 dot2.
// ---------------------------------------------------------------------------
__global__ __launch_bounds__(1024, 4) void rnn_scan_d(
    const uint4* wt3,                // packed W_hh [64][512] uint4 (no restrict)
    const float* __restrict__ H0,    // [128][512]
    float* out,                      // [128][2048][512] (no restrict)
    float* hT)                       // [128][512]
{
    __shared__ uint4   wlds[16][512];   // 128 KB resident W
    __shared__ unsigned hpk[2][256];    // 2 KB packed-f16 h double buffer
    __shared__ float    ps[NH];         // 2 KB upper-half partials

    const int tid  = threadIdx.x;
    const int b    = blockIdx.x;
    const int j    = tid & 511;
    const int half = tid >> 9;

    // --- stage resident W blocks (first 8 of each half), coalesced ---
    #pragma unroll
    for (int pass = 0; pass < 8; ++pass) {
        const int idx = pass * 1024 + tid;        // 0..8191
        const int r   = idx >> 9;                 // resident block 0..15
        const int col = idx & 511;
        const int gb  = (r >> 3) * 32 + (r & 7);  // global k-block
        wlds[r][col] = wt3[(size_t)gb * 512 + col];
    }

    // --- stage h0, packed f16 pairs ---
    if (tid < NH) {
        const float h0v = H0[(size_t)b * NH + tid];
        const float h0o = __shfl_down(h0v, 1);
        if ((tid & 1) == 0) {
            const unsigned lo = __half_as_ushort(__float2half_rn(h0v));
            const unsigned hi = __half_as_ushort(__float2half_rn(h0o));
            hpk[0][tid >> 1] = lo | (hi << 16);
        }
    }
    __syncthreads();   // wlds + h0 ready

    float* outrow = out + (size_t)b * T_SZ * NH + tid;   // reduce role, tid<512
    float xp_cur = (tid < NH) ? outrow[0] : 0.f;
    int cur = 0;
    float hv = 0.f;

    const uint4* wstr = wt3 + (size_t)(half * 32 + 8) * 512 + j;  // stream blocks
    const int wr0 = half * 8;                                      // resident base

    for (int t = 0; t < T_SZ; ++t) {
        float xp_next = 0.f;
        if (tid < NH && t + 1 < T_SZ)
            xp_next = __builtin_nontemporal_load(outrow + (size_t)(t + 1) * NH);

        // this half's packed h: 32 uint4 (256 k = 128 pairs)
        const uint4* hq = reinterpret_cast<const uint4*>(hpk[cur]) + half * 32;
        float acc = 0.f;

        #pragma unroll
        for (int g = 0; g < 8; ++g) {
            {   // 1 LDS-resident block
                const uint4 wv = wlds[wr0 + g][j];
                const uint4 hb = hq[g];           // wave-uniform -> broadcast
                DOT_BLK(wv, hb);
            }
            #pragma unroll
            for (int s = 0; s < 3; ++s) {         // 3 streamed blocks
                const int sb = g * 3 + s;
                const uint4 wv = wstr[(size_t)sb * 512];   // 16B/lane, L2-hit
                const uint4 hb = hq[8 + sb];
                DOT_BLK(wv, hb);
            }
        }

        if (half == 1) ps[j] = acc;
        __syncthreads();   // s1: partials visible

        if (tid < NH) {
            hv = tanhf(acc + ps[tid] + xp_cur);
            __builtin_nontemporal_store(hv, outrow + (size_t)t * NH);
            const float ho = __shfl_down(hv, 1);
            if ((tid & 1) == 0) {
                const unsigned lo = __half_as_ushort(__float2half_rn(hv));
                const unsigned hi = __half_as_ushort(__float2half_rn(ho));
                hpk[cur ^ 1][tid >> 1] = lo | (hi << 16);
            }
            xp_cur = xp_next;
        }
        __syncthreads();   // s2: h[cur^1] complete, ps reads done
        cur ^= 1;
    }
    if (tid < NH) hT[(size_t)b * NH + tid] = hv;
}

// ---------------------------------------------------------------------------
extern "C" void kernel_launch(void* const* d_in, const int* in_sizes, int n_in,
                              void* d_out, int out_size, void* d_ws, size_t ws_size,
                              hipStream_t stream) {
    const float* inputs = (const float*)d_in[0];   // [B, T, NI]
    const float* H0     = (const float*)d_in[1];   // [B, NH]
    const float* W_xh   = (const float*)d_in[2];   // [NI, NH]
    const float* W_hh   = (const float*)d_in[3];   // [NH, NH]
    const float* b_h    = (const float*)d_in[4];   // [NH]

    float* out = (float*)d_out;                        // outs [B,T,NH]
    float* hT  = out + (size_t)B_SZ * T_SZ * NH;       // H_T [B,NH]

    uint4* wt3 = (uint4*)d_ws;                         // 512 KB packed W_hh

    // 0) pack W_hh -> f16 pairs (deterministic, rewritten every launch)
    pack_whh<<<128, 256, 0, stream>>>(W_hh, wt3);

    // 1) input projection -> d_out outs region
    dim3 g1(NH / BN, (B_SZ * T_SZ) / BM);  // (8, 4096)
    proj_gemm<<<g1, 256, 0, stream>>>(inputs, W_xh, b_h, out);

    // 2) zero-sync recurrence: one 1024-thread WG per chain, f16 dot2
    rnn_scan_d<<<128, 1024, 0, stream>>>(wt3, H0, out, hT);
}

// Round 13
// 7910.522 us; speedup vs baseline: 6.7736x; 1.2045x over previous
//
#include <hip/hip_runtime.h>
#include <hip/hip_bf16.h>
#include <hip/hip_fp16.h>
#include <math.h>

#define B_SZ 128
#define T_SZ 2048
#define NI 512
#define NH 512
#define M_TOT (B_SZ * T_SZ)   // 262144

// ---------------------------------------------------------------------------
// f16 helpers
// ---------------------------------------------------------------------------
typedef _Float16 h2_t  __attribute__((ext_vector_type(2)));
typedef _Float16 f16x8 __attribute__((ext_vector_type(8)));
typedef float    f32x4 __attribute__((ext_vector_type(4)));

__device__ __forceinline__ float dot2p(unsigned w, unsigned h, float acc) {
#if __has_builtin(__builtin_amdgcn_fdot2)
    return __builtin_amdgcn_fdot2(__builtin_bit_cast(h2_t, w),
                                  __builtin_bit_cast(h2_t, h), acc, false);
#else
    const h2_t wv = __builtin_bit_cast(h2_t, w);
    const h2_t hv = __builtin_bit_cast(h2_t, h);
    acc = fmaf((float)wv.x, (float)hv.x, acc);
    acc = fmaf((float)wv.y, (float)hv.y, acc);
    return acc;
#endif
}

#define DOT_BLK(WV, HV)                      \
    do {                                     \
        acc = dot2p((WV).x, (HV).x, acc);    \
        acc = dot2p((WV).y, (HV).y, acc);    \
        acc = dot2p((WV).z, (HV).z, acc);    \
        acc = dot2p((WV).w, (HV).w, acc);    \
    } while (0)

__device__ __forceinline__ unsigned pkh2(float a, float b) {
    return (unsigned)__half_as_ushort(__float2half_rn(a)) |
           ((unsigned)__half_as_ushort(__float2half_rn(b)) << 16);
}

// ---------------------------------------------------------------------------
// Kernel 0: pack W_hh into f16-pair k-blocked layout (for the scan).
// Runs AFTER proj_mfma: overwrites the ws region wT used (time-share, total
// ws usage stays at the proven-safe 512 KB).
// ---------------------------------------------------------------------------
__global__ __launch_bounds__(256) void pack_whh(
    const float* __restrict__ W, uint4* __restrict__ wt3)
{
    const int idx = blockIdx.x * 256 + threadIdx.x;  // = kk4*512 + j
    const int j   = idx & 511;
    const int kk4 = idx >> 9;
    const int k0  = kk4 * 8;
    unsigned d[4];
    #pragma unroll
    for (int q = 0; q < 4; ++q)
        d[q] = pkh2(W[(size_t)(k0 + 2 * q) * NH + j],
                    W[(size_t)(k0 + 2 * q + 1) * NH + j]);
    wt3[idx] = make_uint4(d[0], d[1], d[2], d[3]);
}

// ---------------------------------------------------------------------------
// Kernel B: W_xh [K=512][N=512] fp32 -> wT [N][K] f16 (MFMA B^T operand).
// Writes ws+0 (512 KB); consumed by proj_mfma; region then reused by
// pack_whh. 64 WGs, 64x64 tiles via LDS (+1 pad col).
// ---------------------------------------------------------------------------
__global__ __launch_bounds__(256) void transpose_w(
    const float* __restrict__ W, char* __restrict__ wT)
{
    __shared__ float tile[64][65];
    const int kt = blockIdx.x & 7, nt = blockIdx.x >> 3;
    const int t  = threadIdx.x;
    #pragma unroll
    for (int r = 0; r < 4; ++r) {
        const int kl = r * 16 + (t >> 4);
        const int nl = (t & 15) * 4;
        const float4 v = *reinterpret_cast<const float4*>(
            &W[(size_t)(kt * 64 + kl) * NH + nt * 64 + nl]);
        tile[kl][nl + 0] = v.x; tile[kl][nl + 1] = v.y;
        tile[kl][nl + 2] = v.z; tile[kl][nl + 3] = v.w;
    }
    __syncthreads();
    #pragma unroll
    for (int r = 0; r < 4; ++r) {
        const int nl  = r * 16 + (t >> 4);
        const int kl4 = (t & 15) * 4;
        uint2 u;
        u.x = pkh2(tile[kl4 + 0][nl], tile[kl4 + 1][nl]);
        u.y = pkh2(tile[kl4 + 2][nl], tile[kl4 + 3][nl]);
        *reinterpret_cast<uint2*>(
            wT + (size_t)(nt * 64 + nl) * 1024 + (size_t)(kt * 64 + kl4) * 2) = u;
    }
}

// ---------------------------------------------------------------------------
// Kernel 1: x_proj = inputs @ W_xh + b_h via f16 MFMA, fused fp32->f16 A
// staging from the read-only inputs buffer.
// *** r13 FIX ***: the B^T staging in r10/r11/r12 loaded only 64 B of the
// 128 B K-tile row (4 uint4 instead of 8) -> Bs[...][32..63] was
// UNINITIALIZED LDS; the kh=1 fragments read garbage bits (incl. f16 NaN
// encodings) -> NaN. Now stages the full 128 B (byte-count invariant:
// bytes staged == BK*2 per row).
// Tile 64(M) x 256(N), BK=64, 4 waves. Frags (16x16x32): A row=lane&15,
// k=(lane>>4)*8+e; B^T rows same; C col=lane&15, row=(lane>>4)*4+i
// [m89/m121-verified].
// ---------------------------------------------------------------------------
__global__ __launch_bounds__(256) void proj_mfma(
    const float* __restrict__ inp,   // [M_TOT][512] fp32
    const char* __restrict__ wT,     // [512][512] f16 row-major (N,K)
    const float* __restrict__ bias,
    float* __restrict__ C)           // d_out xp region
{
    __shared__ ushort As[64][72];    //  9.2 KB
    __shared__ ushort Bs[256][72];   // 36.9 KB
    const int tid  = threadIdx.x;
    const int w    = tid >> 6;
    const int lane = tid & 63;
    const int l15  = lane & 15, l16 = lane >> 4;
    const int m0   = blockIdx.y * 64;
    const int n0   = blockIdx.x * 256;

    f32x4 acc[4][4] = {};   // [fr (rows)][fc (cols)]

    float bc[4];
    #pragma unroll
    for (int fc = 0; fc < 4; ++fc)
        bc[fc] = bias[n0 + w * 64 + fc * 16 + l15];

    for (int ks = 0; ks < 8; ++ks) {          // K = 512, BK = 64
        __syncthreads();                       // prev frag reads done
        {   // stage A: 64 rows x 64 k fp32 -> f16. thread: row tid>>2,
            // 16-float quarter q=tid&3 (64 B fp32 load -> 32 B LDS write)
            const int r = tid >> 2, q = tid & 3;
            const float* src = inp + (size_t)(m0 + r) * NI + ks * 64 + q * 16;
            const float4 v0 = *reinterpret_cast<const float4*>(src + 0);
            const float4 v1 = *reinterpret_cast<const float4*>(src + 4);
            const float4 v2 = *reinterpret_cast<const float4*>(src + 8);
            const float4 v3 = *reinterpret_cast<const float4*>(src + 12);
            uint4 ua, ub;
            ua.x = pkh2(v0.x, v0.y); ua.y = pkh2(v0.z, v0.w);
            ua.z = pkh2(v1.x, v1.y); ua.w = pkh2(v1.z, v1.w);
            ub.x = pkh2(v2.x, v2.y); ub.y = pkh2(v2.z, v2.w);
            ub.z = pkh2(v3.x, v3.y); ub.w = pkh2(v3.z, v3.w);
            *reinterpret_cast<uint4*>(&As[r][q * 16 + 0]) = ua;
            *reinterpret_cast<uint4*>(&As[r][q * 16 + 8]) = ub;
        }
        {   // stage B^T: 256 rows x 128 B f16 (FULL row: 8 uint4)
            const uint4* src = reinterpret_cast<const uint4*>(
                wT + (size_t)(n0 + tid) * 1024 + ks * 128);
            const uint4 b0 = src[0], b1 = src[1], b2 = src[2], b3 = src[3];
            const uint4 b4 = src[4], b5 = src[5], b6 = src[6], b7 = src[7];
            *reinterpret_cast<uint4*>(&Bs[tid][ 0]) = b0;
            *reinterpret_cast<uint4*>(&Bs[tid][ 8]) = b1;
            *reinterpret_cast<uint4*>(&Bs[tid][16]) = b2;
            *reinterpret_cast<uint4*>(&Bs[tid][24]) = b3;
            *reinterpret_cast<uint4*>(&Bs[tid][32]) = b4;
            *reinterpret_cast<uint4*>(&Bs[tid][40]) = b5;
            *reinterpret_cast<uint4*>(&Bs[tid][48]) = b6;
            *reinterpret_cast<uint4*>(&Bs[tid][56]) = b7;
        }
        __syncthreads();                       // tiles staged
        #pragma unroll
        for (int kh = 0; kh < 2; ++kh) {       // two K=32 mfma groups
            f16x8 a[4], b[4];
            #pragma unroll
            for (int fr = 0; fr < 4; ++fr)
                a[fr] = *reinterpret_cast<const f16x8*>(
                    &As[fr * 16 + l15][kh * 32 + l16 * 8]);
            #pragma unroll
            for (int fc = 0; fc < 4; ++fc)
                b[fc] = *reinterpret_cast<const f16x8*>(
                    &Bs[w * 64 + fc * 16 + l15][kh * 32 + l16 * 8]);
            #pragma unroll
            for (int fr = 0; fr < 4; ++fr)
                #pragma unroll
                for (int fc = 0; fc < 4; ++fc)
                    acc[fr][fc] = __builtin_amdgcn_mfma_f32_16x16x32_f16(
                        a[fr], b[fc], acc[fr][fc], 0, 0, 0);
        }
    }

    // epilogue: C row = m0 + fr*16 + l16*4 + i, col = n0 + w*64 + fc*16 + l15
    #pragma unroll
    for (int fr = 0; fr < 4; ++fr)
        #pragma unroll
        for (int fc = 0; fc < 4; ++fc)
            #pragma unroll
            for (int i = 0; i < 4; ++i) {
                const int row = m0 + fr * 16 + l16 * 4 + i;
                const int col = n0 + w * 64 + fc * 16 + l15;
                C[(size_t)row * NH + col] = acc[fr][fc][i] + bc[fc];
            }
}

// ---------------------------------------------------------------------------
// Kernel 2: ZERO-SYNC scan, f16 dot2 -- byte-identical to round 9 (passed,
// VGPR 52, no spill, 4.06 us/step ~= 95% of the per-CU L2-ingest wall).
// ---------------------------------------------------------------------------
__global__ __launch_bounds__(1024, 4) void rnn_scan_d(
    const uint4* wt3,                // packed W_hh [64][512] uint4 (no restrict)
    const float* __restrict__ H0,    // [128][512]
    float* out,                      // [128][2048][512] (no restrict)
    float* hT)                       // [128][512]
{
    __shared__ uint4   wlds[16][512];   // 128 KB resident W
    __shared__ unsigned hpk[2][256];    // 2 KB packed-f16 h double buffer
    __shared__ float    ps[NH];         // 2 KB upper-half partials

    const int tid  = threadIdx.x;
    const int b    = blockIdx.x;
    const int j    = tid & 511;
    const int half = tid >> 9;

    #pragma unroll
    for (int pass = 0; pass < 8; ++pass) {
        const int idx = pass * 1024 + tid;        // 0..8191
        const int r   = idx >> 9;                 // resident block 0..15
        const int col = idx & 511;
        const int gb  = (r >> 3) * 32 + (r & 7);  // global k-block
        wlds[r][col] = wt3[(size_t)gb * 512 + col];
    }

    if (tid < NH) {
        const float h0v = H0[(size_t)b * NH + tid];
        const float h0o = __shfl_down(h0v, 1);
        if ((tid & 1) == 0)
            hpk[0][tid >> 1] = pkh2(h0v, h0o);
    }
    __syncthreads();

    float* outrow = out + (size_t)b * T_SZ * NH + tid;
    float xp_cur = (tid < NH) ? outrow[0] : 0.f;
    int cur = 0;
    float hv = 0.f;

    const uint4* wstr = wt3 + (size_t)(half * 32 + 8) * 512 + j;
    const int wr0 = half * 8;

    for (int t = 0; t < T_SZ; ++t) {
        float xp_next = 0.f;
        if (tid < NH && t + 1 < T_SZ)
            xp_next = __builtin_nontemporal_load(outrow + (size_t)(t + 1) * NH);

        const uint4* hq = reinterpret_cast<const uint4*>(hpk[cur]) + half * 32;
        float acc = 0.f;

        #pragma unroll
        for (int g = 0; g < 8; ++g) {
            {
                const uint4 wv = wlds[wr0 + g][j];
                const uint4 hb = hq[g];
                DOT_BLK(wv, hb);
            }
            #pragma unroll
            for (int s = 0; s < 3; ++s) {
                const int sb = g * 3 + s;
                const uint4 wv = wstr[(size_t)sb * 512];
                const uint4 hb = hq[8 + sb];
                DOT_BLK(wv, hb);
            }
        }

        if (half == 1) ps[j] = acc;
        __syncthreads();

        if (tid < NH) {
            hv = tanhf(acc + ps[tid] + xp_cur);
            __builtin_nontemporal_store(hv, outrow + (size_t)t * NH);
            const float ho = __shfl_down(hv, 1);
            if ((tid & 1) == 0)
                hpk[cur ^ 1][tid >> 1] = pkh2(hv, ho);
            xp_cur = xp_next;
        }
        __syncthreads();
        cur ^= 1;
    }
    if (tid < NH) hT[(size_t)b * NH + tid] = hv;
}

// ---------------------------------------------------------------------------
extern "C" void kernel_launch(void* const* d_in, const int* in_sizes, int n_in,
                              void* d_out, int out_size, void* d_ws, size_t ws_size,
                              hipStream_t stream) {
    const float* inputs = (const float*)d_in[0];   // [B, T, NI]
    const float* H0     = (const float*)d_in[1];   // [B, NH]
    const float* W_xh   = (const float*)d_in[2];   // [NI, NH]
    const float* W_hh   = (const float*)d_in[3];   // [NH, NH]
    const float* b_h    = (const float*)d_in[4];   // [NH]

    float* out = (float*)d_out;                        // outs [B,T,NH]
    float* hT  = out + (size_t)B_SZ * T_SZ * NH;       // H_T [B,NH]

    // ws TIME-SHARE: [0, 512 KB) holds wT (f16 W_xh^T) for proj, then is
    // overwritten with wt3 (f16 W_hh pack) for the scan.
    char*  wTb = (char*)d_ws;
    uint4* wt3 = (uint4*)d_ws;

    // 1a) W_xh -> f16 transposed [N][K] at ws+0
    transpose_w<<<64, 256, 0, stream>>>(W_xh, wTb);

    // 1b) MFMA projection (fused fp32->f16 A staging) -> d_out xp region
    proj_mfma<<<dim3(NH / 256, M_TOT / 64), 256, 0, stream>>>(
        inputs, wTb, b_h, out);

    // 2a) pack W_hh -> f16 pairs, overwriting ws+0 (wT no longer needed)
    pack_whh<<<128, 256, 0, stream>>>(W_hh, wt3);

    // 2b) zero-sync recurrence (unchanged r9 kernel)
    rnn_scan_d<<<128, 1024, 0, stream>>>(wt3, H0, out, hT);
}

// Round 15
// 7895.043 us; speedup vs baseline: 6.7868x; 1.0020x over previous
//
#include <hip/hip_runtime.h>
#include <hip/hip_bf16.h>
#include <hip/hip_fp16.h>
#include <math.h>

#define B_SZ 128
#define T_SZ 2048
#define NI 512
#define NH 512
#define M_TOT (B_SZ * T_SZ)   // 262144

// ---------------------------------------------------------------------------
// f16 helpers
// ---------------------------------------------------------------------------
typedef _Float16 h2_t  __attribute__((ext_vector_type(2)));
typedef _Float16 f16x8 __attribute__((ext_vector_type(8)));
typedef float    f32x4 __attribute__((ext_vector_type(4)));

__device__ __forceinline__ float dot2p(unsigned w, unsigned h, float acc) {
#if __has_builtin(__builtin_amdgcn_fdot2)
    return __builtin_amdgcn_fdot2(__builtin_bit_cast(h2_t, w),
                                  __builtin_bit_cast(h2_t, h), acc, false);
#else
    const h2_t wv = __builtin_bit_cast(h2_t, w);
    const h2_t hv = __builtin_bit_cast(h2_t, h);
    acc = fmaf((float)wv.x, (float)hv.x, acc);
    acc = fmaf((float)wv.y, (float)hv.y, acc);
    return acc;
#endif
}

#define DOT_BLK(WV, HV)                      \
    do {                                     \
        acc = dot2p((WV).x, (HV).x, acc);    \
        acc = dot2p((WV).y, (HV).y, acc);    \
        acc = dot2p((WV).z, (HV).z, acc);    \
        acc = dot2p((WV).w, (HV).w, acc);    \
    } while (0)

__device__ __forceinline__ unsigned pkh2(float a, float b) {
    return (unsigned)__half_as_ushort(__float2half_rn(a)) |
           ((unsigned)__half_as_ushort(__float2half_rn(b)) << 16);
}

// ---------------------------------------------------------------------------
// Kernel 0: pack W_hh into f16-pair k-blocked layout (for the scan).
// Runs AFTER proj_mfma (ws time-share at 512 KB).
// ---------------------------------------------------------------------------
__global__ __launch_bounds__(256) void pack_whh(
    const float* __restrict__ W, uint4* __restrict__ wt3)
{
    const int idx = blockIdx.x * 256 + threadIdx.x;  // = kk4*512 + j
    const int j   = idx & 511;
    const int kk4 = idx >> 9;
    const int k0  = kk4 * 8;
    unsigned d[4];
    #pragma unroll
    for (int q = 0; q < 4; ++q)
        d[q] = pkh2(W[(size_t)(k0 + 2 * q) * NH + j],
                    W[(size_t)(k0 + 2 * q + 1) * NH + j]);
    wt3[idx] = make_uint4(d[0], d[1], d[2], d[3]);
}

// ---------------------------------------------------------------------------
// Kernel B: W_xh [K=512][N=512] fp32 -> wT [N][K] f16 (MFMA B^T operand).
// ---------------------------------------------------------------------------
__global__ __launch_bounds__(256) void transpose_w(
    const float* __restrict__ W, char* __restrict__ wT)
{
    __shared__ float tile[64][65];
    const int kt = blockIdx.x & 7, nt = blockIdx.x >> 3;
    const int t  = threadIdx.x;
    #pragma unroll
    for (int r = 0; r < 4; ++r) {
        const int kl = r * 16 + (t >> 4);
        const int nl = (t & 15) * 4;
        const float4 v = *reinterpret_cast<const float4*>(
            &W[(size_t)(kt * 64 + kl) * NH + nt * 64 + nl]);
        tile[kl][nl + 0] = v.x; tile[kl][nl + 1] = v.y;
        tile[kl][nl + 2] = v.z; tile[kl][nl + 3] = v.w;
    }
    __syncthreads();
    #pragma unroll
    for (int r = 0; r < 4; ++r) {
        const int nl  = r * 16 + (t >> 4);
        const int kl4 = (t & 15) * 4;
        uint2 u;
        u.x = pkh2(tile[kl4 + 0][nl], tile[kl4 + 1][nl]);
        u.y = pkh2(tile[kl4 + 2][nl], tile[kl4 + 3][nl]);
        *reinterpret_cast<uint2*>(
            wT + (size_t)(nt * 64 + nl) * 1024 + (size_t)(kt * 64 + kl4) * 2) = u;
    }
}

// ---------------------------------------------------------------------------
// Kernel 1: x_proj via f16 MFMA, fused fp32->f16 A staging (r13-exact:
// twice-validated, absmax 0.0039, ~0.2 ms for the whole proj pipeline).
// ---------------------------------------------------------------------------
__global__ __launch_bounds__(256) void proj_mfma(
    const float* __restrict__ inp,   // [M_TOT][512] fp32
    const char* __restrict__ wT,     // [512][512] f16 row-major (N,K)
    const float* __restrict__ bias,
    float* __restrict__ C)           // d_out xp region
{
    __shared__ ushort As[64][72];
    __shared__ ushort Bs[256][72];
    const int tid  = threadIdx.x;
    const int w    = tid >> 6;
    const int lane = tid & 63;
    const int l15  = lane & 15, l16 = lane >> 4;
    const int m0   = blockIdx.y * 64;
    const int n0   = blockIdx.x * 256;

    f32x4 acc[4][4] = {};

    float bc[4];
    #pragma unroll
    for (int fc = 0; fc < 4; ++fc)
        bc[fc] = bias[n0 + w * 64 + fc * 16 + l15];

    for (int ks = 0; ks < 8; ++ks) {
        __syncthreads();
        {   // stage A: 64 rows x 64 k fp32 -> f16
            const int r = tid >> 2, q = tid & 3;
            const float* src = inp + (size_t)(m0 + r) * NI + ks * 64 + q * 16;
            const float4 v0 = *reinterpret_cast<const float4*>(src + 0);
            const float4 v1 = *reinterpret_cast<const float4*>(src + 4);
            const float4 v2 = *reinterpret_cast<const float4*>(src + 8);
            const float4 v3 = *reinterpret_cast<const float4*>(src + 12);
            uint4 ua, ub;
            ua.x = pkh2(v0.x, v0.y); ua.y = pkh2(v0.z, v0.w);
            ua.z = pkh2(v1.x, v1.y); ua.w = pkh2(v1.z, v1.w);
            ub.x = pkh2(v2.x, v2.y); ub.y = pkh2(v2.z, v2.w);
            ub.z = pkh2(v3.x, v3.y); ub.w = pkh2(v3.z, v3.w);
            *reinterpret_cast<uint4*>(&As[r][q * 16 + 0]) = ua;
            *reinterpret_cast<uint4*>(&As[r][q * 16 + 8]) = ub;
        }
        {   // stage B^T: full 128 B row (8 uint4)
            const uint4* src = reinterpret_cast<const uint4*>(
                wT + (size_t)(n0 + tid) * 1024 + ks * 128);
            const uint4 b0 = src[0], b1 = src[1], b2 = src[2], b3 = src[3];
            const uint4 b4 = src[4], b5 = src[5], b6 = src[6], b7 = src[7];
            *reinterpret_cast<uint4*>(&Bs[tid][ 0]) = b0;
            *reinterpret_cast<uint4*>(&Bs[tid][ 8]) = b1;
            *reinterpret_cast<uint4*>(&Bs[tid][16]) = b2;
            *reinterpret_cast<uint4*>(&Bs[tid][24]) = b3;
            *reinterpret_cast<uint4*>(&Bs[tid][32]) = b4;
            *reinterpret_cast<uint4*>(&Bs[tid][40]) = b5;
            *reinterpret_cast<uint4*>(&Bs[tid][48]) = b6;
            *reinterpret_cast<uint4*>(&Bs[tid][56]) = b7;
        }
        __syncthreads();
        #pragma unroll
        for (int kh = 0; kh < 2; ++kh) {
            f16x8 a[4], b[4];
            #pragma unroll
            for (int fr = 0; fr < 4; ++fr)
                a[fr] = *reinterpret_cast<const f16x8*>(
                    &As[fr * 16 + l15][kh * 32 + l16 * 8]);
            #pragma unroll
            for (int fc = 0; fc < 4; ++fc)
                b[fc] = *reinterpret_cast<const f16x8*>(
                    &Bs[w * 64 + fc * 16 + l15][kh * 32 + l16 * 8]);
            #pragma unroll
            for (int fr = 0; fr < 4; ++fr)
                #pragma unroll
                for (int fc = 0; fc < 4; ++fc)
                    acc[fr][fc] = __builtin_amdgcn_mfma_f32_16x16x32_f16(
                        a[fr], b[fc], acc[fr][fc], 0, 0, 0);
        }
    }

    #pragma unroll
    for (int fr = 0; fr < 4; ++fr)
        #pragma unroll
        for (int fc = 0; fc < 4; ++fc)
            #pragma unroll
            for (int i = 0; i < 4; ++i) {
                const int row = m0 + fr * 16 + l16 * 4 + i;
                const int col = n0 + w * 64 + fc * 16 + l15;
                C[(size_t)row * NH + col] = acc[fr][fc][i] + bc[fc];
            }
}

// ---------------------------------------------------------------------------
// Kernel 2: ZERO-SYNC scan, f16 dot2 -- r13-exact (twice-validated: VGPR 52,
// no spill, 3.76 us/step = the measured 102 GB/s per-CU L2-ingest wall).
// r14's 18-block variant (148 KB LDS) diverged nondeterministically under
// graph replay -- reverted; its upside was ~3%.
// ---------------------------------------------------------------------------
__global__ __launch_bounds__(1024, 4) void rnn_scan_d(
    const uint4* wt3,                // packed W_hh [64][512] uint4 (no restrict)
    const float* __restrict__ H0,    // [128][512]
    float* out,                      // [128][2048][512] (no restrict)
    float* hT)                       // [128][512]
{
    __shared__ uint4   wlds[16][512];   // 128 KB resident W
    __shared__ unsigned hpk[2][256];    // 2 KB packed-f16 h double buffer
    __shared__ float    ps[NH];         // 2 KB upper-half partials

    const int tid  = threadIdx.x;
    const int b    = blockIdx.x;
    const int j    = tid & 511;
    const int half = tid >> 9;

    #pragma unroll
    for (int pass = 0; pass < 8; ++pass) {
        const int idx = pass * 1024 + tid;        // 0..8191
        const int r   = idx >> 9;                 // resident block 0..15
        const int col = idx & 511;
        const int gb  = (r >> 3) * 32 + (r & 7);  // global k-block
        wlds[r][col] = wt3[(size_t)gb * 512 + col];
    }

    if (tid < NH) {
        const float h0v = H0[(size_t)b * NH + tid];
        const float h0o = __shfl_down(h0v, 1);
        if ((tid & 1) == 0)
            hpk[0][tid >> 1] = pkh2(h0v, h0o);
    }
    __syncthreads();

    float* outrow = out + (size_t)b * T_SZ * NH + tid;
    float xp_cur = (tid < NH) ? outrow[0] : 0.f;
    int cur = 0;
    float hv = 0.f;

    const uint4* wstr = wt3 + (size_t)(half * 32 + 8) * 512 + j;
    const int wr0 = half * 8;

    for (int t = 0; t < T_SZ; ++t) {
        float xp_next = 0.f;
        if (tid < NH && t + 1 < T_SZ)
            xp_next = __builtin_nontemporal_load(outrow + (size_t)(t + 1) * NH);

        const uint4* hq = reinterpret_cast<const uint4*>(hpk[cur]) + half * 32;
        float acc = 0.f;

        #pragma unroll
        for (int g = 0; g < 8; ++g) {
            {
                const uint4 wv = wlds[wr0 + g][j];
                const uint4 hb = hq[g];
                DOT_BLK(wv, hb);
            }
            #pragma unroll
            for (int s = 0; s < 3; ++s) {
                const int sb = g * 3 + s;
                const uint4 wv = wstr[(size_t)sb * 512];
                const uint4 hb = hq[8 + sb];
                DOT_BLK(wv, hb);
            }
        }

        if (half == 1) ps[j] = acc;
        __syncthreads();

        if (tid < NH) {
            hv = tanhf(acc + ps[tid] + xp_cur);
            __builtin_nontemporal_store(hv, outrow + (size_t)t * NH);
            const float ho = __shfl_down(hv, 1);
            if ((tid & 1) == 0)
                hpk[cur ^ 1][tid >> 1] = pkh2(hv, ho);
            xp_cur = xp_next;
        }
        __syncthreads();
        cur ^= 1;
    }
    if (tid < NH) hT[(size_t)b * NH + tid] = hv;
}

// ---------------------------------------------------------------------------
extern "C" void kernel_launch(void* const* d_in, const int* in_sizes, int n_in,
                              void* d_out, int out_size, void* d_ws, size_t ws_size,
                              hipStream_t stream) {
    const float* inputs = (const float*)d_in[0];   // [B, T, NI]
    const float* H0     = (const float*)d_in[1];   // [B, NH]
    const float* W_xh   = (const float*)d_in[2];   // [NI, NH]
    const float* W_hh   = (const float*)d_in[3];   // [NH, NH]
    const float* b_h    = (const float*)d_in[4];   // [NH]

    float* out = (float*)d_out;                        // outs [B,T,NH]
    float* hT  = out + (size_t)B_SZ * T_SZ * NH;       // H_T [B,NH]

    // ws TIME-SHARE: [0, 512 KB) = wT for proj, then wt3 for the scan.
    char*  wTb = (char*)d_ws;
    uint4* wt3 = (uint4*)d_ws;

    // 1a) W_xh -> f16 transposed [N][K] at ws+0
    transpose_w<<<64, 256, 0, stream>>>(W_xh, wTb);

    // 1b) MFMA projection (fused fp32->f16 A staging) -> d_out xp region
    proj_mfma<<<dim3(NH / 256, M_TOT / 64), 256, 0, stream>>>(
        inputs, wTb, b_h, out);

    // 2a) pack W_hh -> f16 pairs, overwriting ws+0
    pack_whh<<<128, 256, 0, stream>>>(W_hh, wt3);

    // 2b) zero-sync recurrence (r13-exact 16-block LDS-resident W)
    rnn_scan_d<<<128, 1024, 0, stream>>>(wt3, H0, out, hT);
}